// Round 3
// baseline (9655.090 us; speedup 1.0000x reference)
//
#include <hip/hip_runtime.h>

#define S_LEN 512
#define HID   512
#define FEAT  26
#define NCLS  20

typedef short bf16x8 __attribute__((ext_vector_type(8)));
typedef float f32x4  __attribute__((ext_vector_type(4)));

__device__ __forceinline__ unsigned short f2bf(float f) {   // RNE
    unsigned u = __builtin_bit_cast(unsigned, f);
    unsigned r = (u + 0x7FFFu + ((u >> 16) & 1u)) >> 16;
    return (unsigned short)r;
}
__device__ __forceinline__ float sigm(float x) { return 1.f / (1.f + __expf(-x)); }
__device__ __forceinline__ float tanh_f(float x) {
    float xc = fminf(fmaxf(x, -15.f), 15.f);
    float t = __expf(-2.f * xc);
    return (1.f - t) / (1.f + t);
}

// ctr zero + w1/w2 fp32 -> bf16 conversion (once per launch)
__global__ void prep_kernel(const float* __restrict__ w1, const float* __restrict__ w2,
                            unsigned short* __restrict__ w1b, unsigned short* __restrict__ w2b,
                            unsigned* __restrict__ ctr) {
    int i = blockIdx.x * 256 + threadIdx.x;
    if (i < 16 * S_LEN) ctr[i] = 0u;
    if (i < 256 * 512) w1b[i] = f2bf(w1[i]);
    if (i < NCLS * 256) w2b[i] = f2bf(w2[i]);
}

// Fused persistent LSTM + per-step MLP/log-softmax.
// 256 wgs = 16 clusters x 16 wgs. Cluster owns 16 batch rows for all 512 steps;
// wg owns 32 hidden units (128 gate rows); w_hh/w_ih bf16 fragments live in
// registers. h exchanged via 2-slot rotating global bf16 buffer. MLP for step
// t-1 done by wg (t-1)&15 from the staged At tile.
__global__ __launch_bounds__(256, 1) void lstm_fused_kernel(
    const float* __restrict__ x,      // [B][S][FEAT] fp32
    const float* __restrict__ w_ih,   // [2048][FEAT] fp32
    const float* __restrict__ w_hh,   // [2048][HID] fp32
    const float* __restrict__ b_ih,
    const float* __restrict__ b_hh,
    const unsigned short* __restrict__ w1b,  // [256][512] bf16 (pre-converted)
    const float* __restrict__ b1,
    const unsigned short* __restrict__ w2b,  // [20][256] bf16 (pre-converted)
    const float* __restrict__ b2,
    float* __restrict__ out,          // [B][S][NCLS] fp32
    unsigned short* __restrict__ hb,  // [16][2][16][HID] bf16 rotating h
    unsigned* __restrict__ ctr)       // [16][S]
{
    const int tid  = threadIdx.x;
    const int wave = tid >> 6;      // 0..3 == gate index (i,f,g,o)
    const int lane = tid & 63;
    const int quad = lane >> 4;
    const int l16  = lane & 15;
    const int wg   = blockIdx.x;
    const int clust = (wg & 7) * 2 + (wg >= 128 ? 1 : 0);
    const int wic   = (wg >> 3) & 15;
    const int B0    = clust * 16;
    const int U0    = wic * 32;

    __shared__ __align__(16) unsigned short At[16 * 552];   // [16 b][544 + pad] bf16
    __shared__ float zb[16 * 132];                           // [16 b][128 + pad]
    __shared__ __align__(16) unsigned short hid[16 * 264];   // [16 b][256 + pad] bf16
    __shared__ float lg[16 * 24];                            // [16 b][20 + pad]

    // ---- persistent B fragments (RNE fp32->bf16): kk 0..15 = w_hh, kk 16 = w_ih ----
    bf16x8 bB[2][17];
#pragma unroll
    for (int tl = 0; tl < 2; ++tl) {
        const int row = wave * 512 + U0 + tl * 16 + l16;     // gate row in [0,2048)
        const float* wrow = w_hh + (size_t)row * HID;
#pragma unroll
        for (int kk = 0; kk < 16; ++kk) {
            const float* p = wrow + kk * 32 + quad * 8;
            bf16x8 v;
#pragma unroll
            for (int j = 0; j < 8; ++j) v[j] = (short)f2bf(p[j]);
            bB[tl][kk] = v;
        }
        const float* irow = w_ih + (size_t)row * FEAT;
        bf16x8 v;
#pragma unroll
        for (int j = 0; j < 8; ++j) {
            int ftr = quad * 8 + j;
            v[j] = (ftr < FEAT) ? (short)f2bf(irow[ftr]) : (short)0;
        }
        bB[tl][16] = v;
    }

    // ---- gate-phase constants: thread handles (gb, gu) and (gb, gu+16) ----
    const int gb = tid >> 4;
    const int gu = tid & 15;
    float bias[2][4];
#pragma unroll
    for (int uu = 0; uu < 2; ++uu)
#pragma unroll
        for (int g = 0; g < 4; ++g) {
            int r = g * 512 + U0 + gu + uu * 16;
            bias[uu][g] = b_ih[r] + b_hh[r];
        }
    float cst[2] = {0.f, 0.f};

    const int sm = tid >> 4;     // staging row
    const int sc = tid & 15;     // staging chunk
    unsigned* myctr = ctr + clust * S_LEN;
    unsigned short* hbc = hb + (size_t)clust * 2 * 16 * HID;

    for (int t = 0; t <= S_LEN; ++t) {
        const bool last = (t == S_LEN);
        if (last && wic != 15) break;       // only wg15 runs the epilogue MLP

        if (t > 0) {
            if (lane == 0) {                 // per-wave acquire
                while (__hip_atomic_load(myctr + (t - 1), __ATOMIC_RELAXED,
                                         __HIP_MEMORY_SCOPE_AGENT) < 16u)
                    __builtin_amdgcn_s_sleep(4);
                (void)__hip_atomic_load(myctr + (t - 1), __ATOMIC_ACQUIRE,
                                        __HIP_MEMORY_SCOPE_AGENT);
            }
            // stage h_{t-1}: 16 rows x 512 bf16 from rotating slot
            const unsigned short* src =
                hbc + ((t - 1) & 1) * 16 * HID + sm * HID + sc * 32;
            unsigned short* dst = At + sm * 552 + sc * 32;
#pragma unroll
            for (int i = 0; i < 4; ++i)
                *(uint4*)(dst + i * 8) = *(const uint4*)(src + i * 8);
        }
        if (!last) {
            // stage x_t (fp32 -> bf16) into cols 512..543, pairs >= 13 zero
            unsigned pk = 0u;
            if (sc <= 12) {
                float2 xv = *(const float2*)(x + ((size_t)(B0 + sm) * S_LEN + t) * FEAT + sc * 2);
                pk = (unsigned)f2bf(xv.x) | ((unsigned)f2bf(xv.y) << 16);
            }
            *(unsigned*)(At + sm * 552 + 512 + sc * 2) = pk;
        }
        __syncthreads();

        if (!last) {
            f32x4 acc0 = {0.f, 0.f, 0.f, 0.f};
            f32x4 acc1 = {0.f, 0.f, 0.f, 0.f};
            const unsigned short* arow = At + l16 * 552 + quad * 8;
            if (t > 0) {
#pragma unroll
                for (int kk = 0; kk < 17; ++kk) {
                    bf16x8 a = __builtin_bit_cast(bf16x8, *(const uint4*)(arow + kk * 32));
                    acc0 = __builtin_amdgcn_mfma_f32_16x16x32_bf16(a, bB[0][kk], acc0, 0, 0, 0);
                    acc1 = __builtin_amdgcn_mfma_f32_16x16x32_bf16(a, bB[1][kk], acc1, 0, 0, 0);
                }
            } else {  // h0 == 0: only x contributes
                bf16x8 a = __builtin_bit_cast(bf16x8, *(const uint4*)(arow + 16 * 32));
                acc0 = __builtin_amdgcn_mfma_f32_16x16x32_bf16(a, bB[0][16], acc0, 0, 0, 0);
                acc1 = __builtin_amdgcn_mfma_f32_16x16x32_bf16(a, bB[1][16], acc1, 0, 0, 0);
            }
            // z -> LDS: D[m=quad*4+r][n=l16]; zb col = gate*32 + unit
#pragma unroll
            for (int r = 0; r < 4; ++r) {
                zb[(quad * 4 + r) * 132 + wave * 32 + l16]      = acc0[r];
                zb[(quad * 4 + r) * 132 + wave * 32 + 16 + l16] = acc1[r];
            }
            __syncthreads();

            {   // gates
                unsigned short* hrow = hbc + (t & 1) * 16 * HID + gb * HID + U0;
                const float* zrow = zb + gb * 132;
#pragma unroll
                for (int uu = 0; uu < 2; ++uu) {
                    int u = gu + uu * 16;
                    float zi = zrow[u]      + bias[uu][0];
                    float zf = zrow[32 + u] + bias[uu][1];
                    float zg = zrow[64 + u] + bias[uu][2];
                    float zo = zrow[96 + u] + bias[uu][3];
                    float cn = sigm(zf) * cst[uu] + sigm(zi) * tanh_f(zg);
                    cst[uu] = cn;
                    float hv = sigm(zo) * tanh_f(cn);
                    hrow[u] = f2bf(hv);
                }
            }
            __syncthreads();   // all waves' h stores drained before flag
            if (tid == 0)
                __hip_atomic_fetch_add(myctr + t, 1u, __ATOMIC_RELEASE,
                                       __HIP_MEMORY_SCOPE_AGENT);
        }

        // ---- MLP + log_softmax for step tm = t-1 (At holds full h_{tm}) ----
        if (t > 0 && ((t - 1) & 15) == wic) {
            const int tm = t - 1;
            f32x4 a1[4];
#pragma unroll
            for (int nt = 0; nt < 4; ++nt) a1[nt] = (f32x4){0.f, 0.f, 0.f, 0.f};
#pragma unroll
            for (int kk = 0; kk < 16; ++kk) {
                bf16x8 a = __builtin_bit_cast(
                    bf16x8, *(const uint4*)(At + l16 * 552 + kk * 32 + quad * 8));
#pragma unroll
                for (int nt = 0; nt < 4; ++nt) {
                    int n = wave * 64 + nt * 16 + l16;
                    bf16x8 b = __builtin_bit_cast(
                        bf16x8, *(const uint4*)(w1b + (size_t)n * 512 + kk * 32 + quad * 8));
                    a1[nt] = __builtin_amdgcn_mfma_f32_16x16x32_bf16(a, b, a1[nt], 0, 0, 0);
                }
            }
#pragma unroll
            for (int nt = 0; nt < 4; ++nt) {
                int n = wave * 64 + nt * 16 + l16;
                float bv = b1[n];
#pragma unroll
                for (int r = 0; r < 4; ++r) {
                    int m = quad * 4 + r;
                    hid[m * 264 + n] = f2bf(fmaxf(a1[nt][r] + bv, 0.f));
                }
            }
            __syncthreads();
            if (wave == 0) {
                f32x4 a2[2];
                a2[0] = (f32x4){0.f, 0.f, 0.f, 0.f};
                a2[1] = (f32x4){0.f, 0.f, 0.f, 0.f};
#pragma unroll
                for (int kk = 0; kk < 8; ++kk) {
                    bf16x8 a = __builtin_bit_cast(
                        bf16x8, *(const uint4*)(hid + l16 * 264 + kk * 32 + quad * 8));
#pragma unroll
                    for (int nt = 0; nt < 2; ++nt) {
                        int n = nt * 16 + l16;
                        bf16x8 b;
                        if (n < NCLS) {
                            b = __builtin_bit_cast(
                                bf16x8, *(const uint4*)(w2b + (size_t)n * 256 + kk * 32 + quad * 8));
                        } else {
                            uint4 z; z.x = z.y = z.z = z.w = 0u;
                            b = __builtin_bit_cast(bf16x8, z);
                        }
                        a2[nt] = __builtin_amdgcn_mfma_f32_16x16x32_bf16(a, b, a2[nt], 0, 0, 0);
                    }
                }
#pragma unroll
                for (int nt = 0; nt < 2; ++nt) {
                    int n = nt * 16 + l16;
                    if (n < NCLS) {
                        float bv = b2[n];
#pragma unroll
                        for (int r = 0; r < 4; ++r)
                            lg[(quad * 4 + r) * 24 + n] = a2[nt][r] + bv;
                    }
                }
            }
            __syncthreads();
            if (tid < 16) {
                float v[NCLS];
                float mx = -3.4e38f;
#pragma unroll
                for (int c = 0; c < NCLS; ++c) { v[c] = lg[tid * 24 + c]; mx = fmaxf(mx, v[c]); }
                float s = 0.f;
#pragma unroll
                for (int c = 0; c < NCLS; ++c) s += __expf(v[c] - mx);
                float lse = mx + __logf(s);
                float* orow = out + ((size_t)(B0 + tid) * S_LEN + tm) * NCLS;
#pragma unroll
                for (int c = 0; c < NCLS; ++c) orow[c] = v[c] - lse;
            }
        }
    }
}

extern "C" void kernel_launch(void* const* d_in, const int* in_sizes, int n_in,
                              void* d_out, int out_size, void* d_ws, size_t ws_size,
                              hipStream_t stream) {
    const float* x    = (const float*)d_in[0];
    const float* w_ih = (const float*)d_in[1];
    const float* w_hh = (const float*)d_in[2];
    const float* b_ih = (const float*)d_in[3];
    const float* b_hh = (const float*)d_in[4];
    const float* w1   = (const float*)d_in[5];
    const float* b1   = (const float*)d_in[6];
    const float* w2   = (const float*)d_in[7];
    const float* b2   = (const float*)d_in[8];

    // d_ws: hb 512 KB | ctr 32 KB | w1b 256 KB | w2b 10 KB  (~810 KB total)
    char* ws = (char*)d_ws;
    unsigned short* hb  = (unsigned short*)ws;                       // 16*2*16*512 bf16
    unsigned*       ctr = (unsigned*)(ws + 524288);
    unsigned short* w1b = (unsigned short*)(ws + 524288 + 32768);
    unsigned short* w2b = (unsigned short*)(ws + 524288 + 32768 + 262144);

    prep_kernel<<<512, 256, 0, stream>>>(w1, w2, w1b, w2b, ctr);
    lstm_fused_kernel<<<256, 256, 0, stream>>>(x, w_ih, w_hh, b_ih, b_hh,
                                               w1b, b1, w2b, b2,
                                               (float*)d_out, hb, ctr);
}

// Round 4
// 3893.324 us; speedup vs baseline: 2.4799x; 2.4799x over previous
//
#include <hip/hip_runtime.h>

#define S_LEN 512
#define HID   512
#define FEAT  26
#define NCLS  20

typedef short bf16x8 __attribute__((ext_vector_type(8)));
typedef float f32x4  __attribute__((ext_vector_type(4)));

__device__ __forceinline__ unsigned short f2bf(float f) {   // RNE
    unsigned u = __builtin_bit_cast(unsigned, f);
    unsigned r = (u + 0x7FFFu + ((u >> 16) & 1u)) >> 16;
    return (unsigned short)r;
}
__device__ __forceinline__ float sigm(float x) { return 1.f / (1.f + __expf(-x)); }
__device__ __forceinline__ float tanh_f(float x) {
    float xc = fminf(fmaxf(x, -15.f), 15.f);
    float t = __expf(-2.f * xc);
    return (1.f - t) / (1.f + t);
}

// 4 coherent (MALL, bypass L1/L2) 16B loads + drain. No buffer_inv needed.
__device__ __forceinline__ void load4_coherent(const unsigned short* p,
                                               uint4& a0, uint4& a1, uint4& a2, uint4& a3) {
    asm volatile(
        "global_load_dwordx4 %0, %4, off sc0 sc1\n\t"
        "global_load_dwordx4 %1, %5, off sc0 sc1\n\t"
        "global_load_dwordx4 %2, %6, off sc0 sc1\n\t"
        "global_load_dwordx4 %3, %7, off sc0 sc1\n\t"
        "s_waitcnt vmcnt(0)"
        : "=&v"(a0), "=&v"(a1), "=&v"(a2), "=&v"(a3)
        : "v"(p), "v"(p + 8), "v"(p + 16), "v"(p + 24)
        : "memory");
}
// coherent dword store + drain (ack from coherence point). No buffer_wbl2 needed.
__device__ __forceinline__ void store_coherent(unsigned short* p, unsigned d) {
    asm volatile(
        "global_store_dword %0, %1, off sc0 sc1\n\t"
        "s_waitcnt vmcnt(0)"
        :: "v"(p), "v"(d) : "memory");
}

// ctr zero + w1/w2 fp32 -> bf16 conversion (once per launch)
__global__ void prep_kernel(const float* __restrict__ w1, const float* __restrict__ w2,
                            unsigned short* __restrict__ w1b, unsigned short* __restrict__ w2b,
                            unsigned* __restrict__ ctr) {
    int i = blockIdx.x * 256 + threadIdx.x;
    if (i < 16 * S_LEN) ctr[i] = 0u;
    if (i < 256 * 512) w1b[i] = f2bf(w1[i]);
    if (i < NCLS * 256) w2b[i] = f2bf(w2[i]);
}

// Fused persistent LSTM + per-step MLP/log-softmax.
// 256 wgs = 16 clusters x 16 wgs; cluster owns 16 batch rows, wg owns 32 hidden
// units (128 gate rows); w_hh/w_ih bf16 fragments in registers. h exchanged via
// 2-slot rotating buffer using sc0sc1 coherent accesses + RELAXED flag atomics
// (no buffer_inv / buffer_wbl2 on the critical path).
__global__ __launch_bounds__(256, 1) void lstm_fused_kernel(
    const float* __restrict__ x,      // [B][S][FEAT] fp32
    const float* __restrict__ w_ih,   // [2048][FEAT] fp32
    const float* __restrict__ w_hh,   // [2048][HID] fp32
    const float* __restrict__ b_ih,
    const float* __restrict__ b_hh,
    const unsigned short* __restrict__ w1b,  // [256][512] bf16
    const float* __restrict__ b1,
    const unsigned short* __restrict__ w2b,  // [20][256] bf16
    const float* __restrict__ b2,
    float* __restrict__ out,          // [B][S][NCLS] fp32
    unsigned short* __restrict__ hb,  // [16][2][16][HID] bf16 rotating h
    unsigned* __restrict__ ctr)       // [16][S]
{
    const int tid  = threadIdx.x;
    const int wave = tid >> 6;      // 0..3 == gate index (i,f,g,o)
    const int lane = tid & 63;
    const int quad = lane >> 4;
    const int l16  = lane & 15;
    const int wg   = blockIdx.x;
    const int clust = (wg & 7) * 2 + (wg >= 128 ? 1 : 0);
    const int wic   = (wg >> 3) & 15;
    const int B0    = clust * 16;
    const int U0    = wic * 32;

    __shared__ __align__(16) unsigned short At[16 * 552];   // [16 b][544 + pad] bf16
    __shared__ float zb[16 * 132];                           // [16 b][128 + pad]
    __shared__ __align__(16) unsigned short hid[16 * 264];   // [16 b][256 + pad] bf16
    __shared__ float lg[16 * 24];                            // [16 b][20 + pad]

    // ---- persistent B fragments (RNE fp32->bf16): kk 0..15 = w_hh, kk 16 = w_ih ----
    bf16x8 bB[2][17];
#pragma unroll
    for (int tl = 0; tl < 2; ++tl) {
        const int row = wave * 512 + U0 + tl * 16 + l16;     // gate row in [0,2048)
        const float* wrow = w_hh + (size_t)row * HID;
#pragma unroll
        for (int kk = 0; kk < 16; ++kk) {
            const float* p = wrow + kk * 32 + quad * 8;
            bf16x8 v;
#pragma unroll
            for (int j = 0; j < 8; ++j) v[j] = (short)f2bf(p[j]);
            bB[tl][kk] = v;
        }
        const float* irow = w_ih + (size_t)row * FEAT;
        bf16x8 v;
#pragma unroll
        for (int j = 0; j < 8; ++j) {
            int ftr = quad * 8 + j;
            v[j] = (ftr < FEAT) ? (short)f2bf(irow[ftr]) : (short)0;
        }
        bB[tl][16] = v;
    }

    // ---- gate-phase constants: thread (gb,gu) handles units 2gu, 2gu+1 ----
    const int gb = tid >> 4;
    const int gu = tid & 15;
    float bias[2][4];
#pragma unroll
    for (int uu = 0; uu < 2; ++uu)
#pragma unroll
        for (int g = 0; g < 4; ++g) {
            int r = g * 512 + U0 + 2 * gu + uu;
            bias[uu][g] = b_ih[r] + b_hh[r];
        }
    float cst[2] = {0.f, 0.f};

    const int sm = tid >> 4;     // staging row
    const int sc = tid & 15;     // staging chunk
    unsigned* myctr = ctr + clust * S_LEN;
    unsigned short* hbc = hb + (size_t)clust * 2 * 16 * HID;

    for (int t = 0; t <= S_LEN; ++t) {
        const bool last = (t == S_LEN);
        if (last && wic != 15) break;       // only wg15 runs the epilogue MLP

        if (t > 0) {
            if (tid == 0) {                  // single poller per wg, relaxed
                while (__hip_atomic_load(myctr + (t - 1), __ATOMIC_RELAXED,
                                         __HIP_MEMORY_SCOPE_AGENT) < 16u)
                    __builtin_amdgcn_s_sleep(2);
            }
            __syncthreads();
            // stage h_{t-1}: 16 rows x 512 bf16, coherent loads (bypass L1/L2)
            const unsigned short* src =
                hbc + ((t - 1) & 1) * 16 * HID + sm * HID + sc * 32;
            unsigned short* dst = At + sm * 552 + sc * 32;
            uint4 a0, a1, a2, a3;
            load4_coherent(src, a0, a1, a2, a3);
            *(uint4*)(dst)      = a0;
            *(uint4*)(dst + 8)  = a1;
            *(uint4*)(dst + 16) = a2;
            *(uint4*)(dst + 24) = a3;
        }
        if (!last) {
            // stage x_t (fp32 -> bf16) into cols 512..543, pairs >= 13 zero
            unsigned pk = 0u;
            if (sc <= 12) {
                float2 xv = *(const float2*)(x + ((size_t)(B0 + sm) * S_LEN + t) * FEAT + sc * 2);
                pk = (unsigned)f2bf(xv.x) | ((unsigned)f2bf(xv.y) << 16);
            }
            *(unsigned*)(At + sm * 552 + 512 + sc * 2) = pk;
        }
        __syncthreads();

        if (!last) {
            f32x4 acc0 = {0.f, 0.f, 0.f, 0.f};
            f32x4 acc1 = {0.f, 0.f, 0.f, 0.f};
            const unsigned short* arow = At + l16 * 552 + quad * 8;
            if (t > 0) {
#pragma unroll
                for (int kk = 0; kk < 17; ++kk) {
                    bf16x8 a = __builtin_bit_cast(bf16x8, *(const uint4*)(arow + kk * 32));
                    acc0 = __builtin_amdgcn_mfma_f32_16x16x32_bf16(a, bB[0][kk], acc0, 0, 0, 0);
                    acc1 = __builtin_amdgcn_mfma_f32_16x16x32_bf16(a, bB[1][kk], acc1, 0, 0, 0);
                }
            } else {  // h0 == 0: only x contributes
                bf16x8 a = __builtin_bit_cast(bf16x8, *(const uint4*)(arow + 16 * 32));
                acc0 = __builtin_amdgcn_mfma_f32_16x16x32_bf16(a, bB[0][16], acc0, 0, 0, 0);
                acc1 = __builtin_amdgcn_mfma_f32_16x16x32_bf16(a, bB[1][16], acc1, 0, 0, 0);
            }
            // z -> LDS: D[m=quad*4+r][n=l16]; zb col = gate*32 + unit
#pragma unroll
            for (int r = 0; r < 4; ++r) {
                zb[(quad * 4 + r) * 132 + wave * 32 + l16]      = acc0[r];
                zb[(quad * 4 + r) * 132 + wave * 32 + 16 + l16] = acc1[r];
            }
            __syncthreads();

            {   // gates: units 2gu, 2gu+1 -> one packed coherent dword store
                const float* zrow = zb + gb * 132;
                unsigned short hv2[2];
#pragma unroll
                for (int uu = 0; uu < 2; ++uu) {
                    int u = 2 * gu + uu;
                    float zi = zrow[u]      + bias[uu][0];
                    float zf = zrow[32 + u] + bias[uu][1];
                    float zg = zrow[64 + u] + bias[uu][2];
                    float zo = zrow[96 + u] + bias[uu][3];
                    float cn = sigm(zf) * cst[uu] + sigm(zi) * tanh_f(zg);
                    cst[uu] = cn;
                    hv2[uu] = f2bf(sigm(zo) * tanh_f(cn));
                }
                unsigned short* hp =
                    hbc + (t & 1) * 16 * HID + gb * HID + U0 + 2 * gu;
                store_coherent(hp, (unsigned)hv2[0] | ((unsigned)hv2[1] << 16));
            }
            __syncthreads();   // all waves' coherent stores drained before flag
            if (tid == 0)
                __hip_atomic_fetch_add(myctr + t, 1u, __ATOMIC_RELAXED,
                                       __HIP_MEMORY_SCOPE_AGENT);
        }

        // ---- MLP + log_softmax for step tm = t-1 (At holds full h_{tm}) ----
        if (t > 0 && ((t - 1) & 15) == wic) {
            const int tm = t - 1;
            f32x4 a1[4];
#pragma unroll
            for (int nt = 0; nt < 4; ++nt) a1[nt] = (f32x4){0.f, 0.f, 0.f, 0.f};
#pragma unroll
            for (int kk = 0; kk < 16; ++kk) {
                bf16x8 a = __builtin_bit_cast(
                    bf16x8, *(const uint4*)(At + l16 * 552 + kk * 32 + quad * 8));
#pragma unroll
                for (int nt = 0; nt < 4; ++nt) {
                    int n = wave * 64 + nt * 16 + l16;
                    bf16x8 b = __builtin_bit_cast(
                        bf16x8, *(const uint4*)(w1b + (size_t)n * 512 + kk * 32 + quad * 8));
                    a1[nt] = __builtin_amdgcn_mfma_f32_16x16x32_bf16(a, b, a1[nt], 0, 0, 0);
                }
            }
#pragma unroll
            for (int nt = 0; nt < 4; ++nt) {
                int n = wave * 64 + nt * 16 + l16;
                float bv = b1[n];
#pragma unroll
                for (int r = 0; r < 4; ++r) {
                    int m = quad * 4 + r;
                    hid[m * 264 + n] = f2bf(fmaxf(a1[nt][r] + bv, 0.f));
                }
            }
            __syncthreads();
            if (wave == 0) {
                f32x4 a2[2];
                a2[0] = (f32x4){0.f, 0.f, 0.f, 0.f};
                a2[1] = (f32x4){0.f, 0.f, 0.f, 0.f};
#pragma unroll
                for (int kk = 0; kk < 8; ++kk) {
                    bf16x8 a = __builtin_bit_cast(
                        bf16x8, *(const uint4*)(hid + l16 * 264 + kk * 32 + quad * 8));
#pragma unroll
                    for (int nt = 0; nt < 2; ++nt) {
                        int n = nt * 16 + l16;
                        bf16x8 b;
                        if (n < NCLS) {
                            b = __builtin_bit_cast(
                                bf16x8, *(const uint4*)(w2b + (size_t)n * 256 + kk * 32 + quad * 8));
                        } else {
                            uint4 z; z.x = z.y = z.z = z.w = 0u;
                            b = __builtin_bit_cast(bf16x8, z);
                        }
                        a2[nt] = __builtin_amdgcn_mfma_f32_16x16x32_bf16(a, b, a2[nt], 0, 0, 0);
                    }
                }
#pragma unroll
                for (int nt = 0; nt < 2; ++nt) {
                    int n = nt * 16 + l16;
                    if (n < NCLS) {
                        float bv = b2[n];
#pragma unroll
                        for (int r = 0; r < 4; ++r)
                            lg[(quad * 4 + r) * 24 + n] = a2[nt][r] + bv;
                    }
                }
            }
            __syncthreads();
            if (tid < 16) {
                float v[NCLS];
                float mx = -3.4e38f;
#pragma unroll
                for (int c = 0; c < NCLS; ++c) { v[c] = lg[tid * 24 + c]; mx = fmaxf(mx, v[c]); }
                float s = 0.f;
#pragma unroll
                for (int c = 0; c < NCLS; ++c) s += __expf(v[c] - mx);
                float lse = mx + __logf(s);
                float* orow = out + ((size_t)(B0 + tid) * S_LEN + tm) * NCLS;
#pragma unroll
                for (int c = 0; c < NCLS; ++c) orow[c] = v[c] - lse;
            }
        }
    }
}

extern "C" void kernel_launch(void* const* d_in, const int* in_sizes, int n_in,
                              void* d_out, int out_size, void* d_ws, size_t ws_size,
                              hipStream_t stream) {
    const float* x    = (const float*)d_in[0];
    const float* w_ih = (const float*)d_in[1];
    const float* w_hh = (const float*)d_in[2];
    const float* b_ih = (const float*)d_in[3];
    const float* b_hh = (const float*)d_in[4];
    const float* w1   = (const float*)d_in[5];
    const float* b1   = (const float*)d_in[6];
    const float* w2   = (const float*)d_in[7];
    const float* b2   = (const float*)d_in[8];

    // d_ws: hb 512 KB | ctr 32 KB | w1b 256 KB | w2b 10 KB  (~810 KB total)
    char* ws = (char*)d_ws;
    unsigned short* hb  = (unsigned short*)ws;
    unsigned*       ctr = (unsigned*)(ws + 524288);
    unsigned short* w1b = (unsigned short*)(ws + 524288 + 32768);
    unsigned short* w2b = (unsigned short*)(ws + 524288 + 32768 + 262144);

    prep_kernel<<<512, 256, 0, stream>>>(w1, w2, w1b, w2b, ctr);
    lstm_fused_kernel<<<256, 256, 0, stream>>>(x, w_ih, w_hh, b_ih, b_hh,
                                               w1b, b1, w2b, b2,
                                               (float*)d_out, hb, ctr);
}

// Round 5
// 2896.777 us; speedup vs baseline: 3.3330x; 1.3440x over previous
//
#include <hip/hip_runtime.h>

#define S_LEN 512
#define HID   512
#define FEAT  26
#define NCLS  20
#define DRING 16

typedef short bf16x8 __attribute__((ext_vector_type(8)));
typedef float f32x4  __attribute__((ext_vector_type(4)));

__device__ __forceinline__ unsigned short f2bf(float f) {   // RNE
    unsigned u = __builtin_bit_cast(unsigned, f);
    unsigned r = (u + 0x7FFFu + ((u >> 16) & 1u)) >> 16;
    return (unsigned short)r;
}
__device__ __forceinline__ float sigm(float x) { return 1.f / (1.f + __expf(-x)); }
__device__ __forceinline__ float tanh_f(float x) {
    float xc = fminf(fmaxf(x, -15.f), 15.f);
    float t = __expf(-2.f * xc);
    return (1.f - t) / (1.f + t);
}

// 4 coherent (MALL, bypass L1/L2) 16B loads + drain.
__device__ __forceinline__ void load4_coherent(const unsigned short* p,
                                               uint4& a0, uint4& a1, uint4& a2, uint4& a3) {
    asm volatile(
        "global_load_dwordx4 %0, %4, off sc0 sc1\n\t"
        "global_load_dwordx4 %1, %5, off sc0 sc1\n\t"
        "global_load_dwordx4 %2, %6, off sc0 sc1\n\t"
        "global_load_dwordx4 %3, %7, off sc0 sc1\n\t"
        "s_waitcnt vmcnt(0)"
        : "=&v"(a0), "=&v"(a1), "=&v"(a2), "=&v"(a3)
        : "v"(p), "v"(p + 8), "v"(p + 16), "v"(p + 24)
        : "memory");
}
// coherent dword store + drain.
__device__ __forceinline__ void store_coherent(unsigned short* p, unsigned d) {
    asm volatile(
        "global_store_dword %0, %1, off sc0 sc1\n\t"
        "s_waitcnt vmcnt(0)"
        :: "v"(p), "v"(d) : "memory");
}

// zero ctr+done, convert w1/w2 fp32 -> bf16 (once per launch)
__global__ void prep_kernel(const float* __restrict__ w1, const float* __restrict__ w2,
                            unsigned short* __restrict__ w1b, unsigned short* __restrict__ w2b,
                            unsigned* __restrict__ ctrdone) {
    int i = blockIdx.x * 256 + threadIdx.x;
    if (i < 16 * S_LEN + 1024) ctrdone[i] = 0u;   // ctr (8192) + done (1024) contiguous
    if (i < 256 * 512) w1b[i] = f2bf(w1[i]);
    if (i < NCLS * 256) w2b[i] = f2bf(w2[i]);
}

// 320 wgs: wg<256 LSTM (16 clusters x 16 wgs), wg>=256 MLP (16 clusters x 4 wgs).
// LSTM: cluster owns 16 batch rows, wg owns 32 hidden units; w_hh/w_ih in regs;
// h exchanged via 16-slot ring with sc0sc1 coherent accesses + relaxed flags.
// MLP wgs consume h slots asynchronously (steps t==m mod 4) -> off critical path.
__global__ __launch_bounds__(256, 2) void lstm_fused_kernel(
    const float* __restrict__ x,      // [B][S][FEAT] fp32
    const float* __restrict__ w_ih,   // [2048][FEAT] fp32
    const float* __restrict__ w_hh,   // [2048][HID] fp32
    const float* __restrict__ b_ih,
    const float* __restrict__ b_hh,
    const unsigned short* __restrict__ w1b,  // [256][512] bf16
    const float* __restrict__ b1,
    const unsigned short* __restrict__ w2b,  // [20][256] bf16
    const float* __restrict__ b2,
    float* __restrict__ out,          // [B][S][NCLS] fp32
    unsigned short* __restrict__ hb,  // [16][DRING][16][HID] bf16 ring
    unsigned* __restrict__ ctr,       // [16][S] arrival counters
    unsigned* __restrict__ done)      // [16][4] x 16-uint stride: MLP progress
{
    const int tid  = threadIdx.x;
    const int wave = tid >> 6;
    const int lane = tid & 63;
    const int quad = lane >> 4;
    const int l16  = lane & 15;
    const int wg   = blockIdx.x;

    __shared__ __align__(16) unsigned short At[16 * 552];   // [16][544+pad] bf16
    __shared__ float zb[16 * 132];
    __shared__ __align__(16) unsigned short hid[16 * 264];
    __shared__ float lg[16 * 24];

    if (wg < 256) {
        // ======================= LSTM role =======================
        const int clust = (wg & 7) * 2 + (wg >= 128 ? 1 : 0);
        const int wic   = (wg >> 3) & 15;
        const int B0    = clust * 16;
        const int U0    = wic * 32;

        // persistent B fragments: kk 0..15 = w_hh, kk 16 = w_ih
        bf16x8 bB[2][17];
#pragma unroll
        for (int tl = 0; tl < 2; ++tl) {
            const int row = wave * 512 + U0 + tl * 16 + l16;
            const float* wrow = w_hh + (size_t)row * HID;
#pragma unroll
            for (int kk = 0; kk < 16; ++kk) {
                const float* p = wrow + kk * 32 + quad * 8;
                bf16x8 v;
#pragma unroll
                for (int j = 0; j < 8; ++j) v[j] = (short)f2bf(p[j]);
                bB[tl][kk] = v;
            }
            const float* irow = w_ih + (size_t)row * FEAT;
            bf16x8 v;
#pragma unroll
            for (int j = 0; j < 8; ++j) {
                int ftr = quad * 8 + j;
                v[j] = (ftr < FEAT) ? (short)f2bf(irow[ftr]) : (short)0;
            }
            bB[tl][16] = v;
        }

        // gate-phase: thread (gb,gu) handles units 2gu, 2gu+1
        const int gb = tid >> 4;
        const int gu = tid & 15;
        float bias[2][4];
#pragma unroll
        for (int uu = 0; uu < 2; ++uu)
#pragma unroll
            for (int g = 0; g < 4; ++g) {
                int r = g * 512 + U0 + 2 * gu + uu;
                bias[uu][g] = b_ih[r] + b_hh[r];
            }
        float cst[2] = {0.f, 0.f};

        const int sm = tid >> 4;
        const int sc = tid & 15;
        unsigned* myctr = ctr + clust * S_LEN;
        unsigned short* hbc = hb + (size_t)clust * DRING * 16 * HID;

        for (int t = 0; t < S_LEN; ++t) {
            // stage x_t first (independent of h -> overlaps the spin)
            {
                unsigned pk = 0u;
                if (sc <= 12) {
                    float2 xv = *(const float2*)(x + ((size_t)(B0 + sm) * S_LEN + t) * FEAT + sc * 2);
                    pk = (unsigned)f2bf(xv.x) | ((unsigned)f2bf(xv.y) << 16);
                }
                *(unsigned*)(At + sm * 552 + 512 + sc * 2) = pk;
            }
            if (t > 0) {
                if (tid == 0) {
                    while (__hip_atomic_load(myctr + (t - 1), __ATOMIC_RELAXED,
                                             __HIP_MEMORY_SCOPE_AGENT) < 16u)
                        __builtin_amdgcn_s_sleep(2);
                    if (t >= DRING) {   // backpressure: slot t&15 must be consumed
                        unsigned* dn = done + clust * 64 + (t & 3) * 16;
                        while (__hip_atomic_load(dn, __ATOMIC_RELAXED,
                                                 __HIP_MEMORY_SCOPE_AGENT) < (unsigned)(t - DRING + 1))
                            __builtin_amdgcn_s_sleep(2);
                    }
                }
                __syncthreads();
                // stage h_{t-1} from ring slot (t-1)&15, coherent
                const unsigned short* src =
                    hbc + ((t - 1) & (DRING - 1)) * 16 * HID + sm * HID + sc * 32;
                unsigned short* dst = At + sm * 552 + sc * 32;
                uint4 a0, a1, a2, a3;
                load4_coherent(src, a0, a1, a2, a3);
                *(uint4*)(dst)      = a0;
                *(uint4*)(dst + 8)  = a1;
                *(uint4*)(dst + 16) = a2;
                *(uint4*)(dst + 24) = a3;
            }
            __syncthreads();

            f32x4 acc0 = {0.f, 0.f, 0.f, 0.f};
            f32x4 acc1 = {0.f, 0.f, 0.f, 0.f};
            const unsigned short* arow = At + l16 * 552 + quad * 8;
            if (t > 0) {
#pragma unroll
                for (int kk = 0; kk < 17; ++kk) {
                    bf16x8 a = __builtin_bit_cast(bf16x8, *(const uint4*)(arow + kk * 32));
                    acc0 = __builtin_amdgcn_mfma_f32_16x16x32_bf16(a, bB[0][kk], acc0, 0, 0, 0);
                    acc1 = __builtin_amdgcn_mfma_f32_16x16x32_bf16(a, bB[1][kk], acc1, 0, 0, 0);
                }
            } else {
                bf16x8 a = __builtin_bit_cast(bf16x8, *(const uint4*)(arow + 16 * 32));
                acc0 = __builtin_amdgcn_mfma_f32_16x16x32_bf16(a, bB[0][16], acc0, 0, 0, 0);
                acc1 = __builtin_amdgcn_mfma_f32_16x16x32_bf16(a, bB[1][16], acc1, 0, 0, 0);
            }
#pragma unroll
            for (int r = 0; r < 4; ++r) {
                zb[(quad * 4 + r) * 132 + wave * 32 + l16]      = acc0[r];
                zb[(quad * 4 + r) * 132 + wave * 32 + 16 + l16] = acc1[r];
            }
            __syncthreads();

            {   // gates -> one packed coherent dword store into ring slot t&15
                const float* zrow = zb + gb * 132;
                unsigned short hv2[2];
#pragma unroll
                for (int uu = 0; uu < 2; ++uu) {
                    int u = 2 * gu + uu;
                    float zi = zrow[u]      + bias[uu][0];
                    float zf = zrow[32 + u] + bias[uu][1];
                    float zg = zrow[64 + u] + bias[uu][2];
                    float zo = zrow[96 + u] + bias[uu][3];
                    float cn = sigm(zf) * cst[uu] + sigm(zi) * tanh_f(zg);
                    cst[uu] = cn;
                    hv2[uu] = f2bf(sigm(zo) * tanh_f(cn));
                }
                unsigned short* hp =
                    hbc + (t & (DRING - 1)) * 16 * HID + gb * HID + U0 + 2 * gu;
                store_coherent(hp, (unsigned)hv2[0] | ((unsigned)hv2[1] << 16));
            }
            __syncthreads();
            if (tid == 0)
                __hip_atomic_fetch_add(myctr + t, 1u, __ATOMIC_RELAXED,
                                       __HIP_MEMORY_SCOPE_AGENT);
        }
    } else {
        // ======================= MLP role =======================
        const int mwg  = wg - 256;
        const int mc   = mwg >> 2;      // cluster
        const int m    = mwg & 3;       // phase: steps t == m (mod 4)
        const int B0   = mc * 16;
        unsigned* myctr = ctr + mc * S_LEN;
        unsigned* mydone = done + mc * 64 + m * 16;
        const unsigned short* hbc = hb + (size_t)mc * DRING * 16 * HID;
        const int sm = tid >> 4;
        const int sc = tid & 15;

        for (int t = m; t < S_LEN; t += 4) {
            if (tid == 0) {
                while (__hip_atomic_load(myctr + t, __ATOMIC_RELAXED,
                                         __HIP_MEMORY_SCOPE_AGENT) < 16u)
                    __builtin_amdgcn_s_sleep(8);
            }
            __syncthreads();
            {   // stage h_t from ring slot t&15 into At
                const unsigned short* src =
                    hbc + (t & (DRING - 1)) * 16 * HID + sm * HID + sc * 32;
                unsigned short* dst = At + sm * 552 + sc * 32;
                uint4 a0, a1, a2, a3;
                load4_coherent(src, a0, a1, a2, a3);
                *(uint4*)(dst)      = a0;
                *(uint4*)(dst + 8)  = a1;
                *(uint4*)(dst + 16) = a2;
                *(uint4*)(dst + 24) = a3;
            }
            __syncthreads();
            if (tid == 0)   // slot consumed: release backpressure
                __hip_atomic_store(mydone, (unsigned)(t + 1), __ATOMIC_RELAXED,
                                   __HIP_MEMORY_SCOPE_AGENT);

            // GEMM1: [16 x 512] @ [512 x 256] (all 4 waves)
            f32x4 a1[4];
#pragma unroll
            for (int nt = 0; nt < 4; ++nt) a1[nt] = (f32x4){0.f, 0.f, 0.f, 0.f};
#pragma unroll
            for (int kk = 0; kk < 16; ++kk) {
                bf16x8 a = __builtin_bit_cast(
                    bf16x8, *(const uint4*)(At + l16 * 552 + kk * 32 + quad * 8));
#pragma unroll
                for (int nt = 0; nt < 4; ++nt) {
                    int n = wave * 64 + nt * 16 + l16;
                    bf16x8 b = __builtin_bit_cast(
                        bf16x8, *(const uint4*)(w1b + (size_t)n * 512 + kk * 32 + quad * 8));
                    a1[nt] = __builtin_amdgcn_mfma_f32_16x16x32_bf16(a, b, a1[nt], 0, 0, 0);
                }
            }
#pragma unroll
            for (int nt = 0; nt < 4; ++nt) {
                int n = wave * 64 + nt * 16 + l16;
                float bv = b1[n];
#pragma unroll
                for (int r = 0; r < 4; ++r) {
                    int mm = quad * 4 + r;
                    hid[mm * 264 + n] = f2bf(fmaxf(a1[nt][r] + bv, 0.f));
                }
            }
            __syncthreads();
            if (wave == 0) {   // GEMM2: [16 x 256] @ [256 x 20(pad32)]
                f32x4 a2[2];
                a2[0] = (f32x4){0.f, 0.f, 0.f, 0.f};
                a2[1] = (f32x4){0.f, 0.f, 0.f, 0.f};
#pragma unroll
                for (int kk = 0; kk < 8; ++kk) {
                    bf16x8 a = __builtin_bit_cast(
                        bf16x8, *(const uint4*)(hid + l16 * 264 + kk * 32 + quad * 8));
#pragma unroll
                    for (int nt = 0; nt < 2; ++nt) {
                        int n = nt * 16 + l16;
                        bf16x8 b;
                        if (n < NCLS) {
                            b = __builtin_bit_cast(
                                bf16x8, *(const uint4*)(w2b + (size_t)n * 256 + kk * 32 + quad * 8));
                        } else {
                            uint4 z; z.x = z.y = z.z = z.w = 0u;
                            b = __builtin_bit_cast(bf16x8, z);
                        }
                        a2[nt] = __builtin_amdgcn_mfma_f32_16x16x32_bf16(a, b, a2[nt], 0, 0, 0);
                    }
                }
#pragma unroll
                for (int nt = 0; nt < 2; ++nt) {
                    int n = nt * 16 + l16;
                    if (n < NCLS) {
                        float bv = b2[n];
#pragma unroll
                        for (int r = 0; r < 4; ++r)
                            lg[(quad * 4 + r) * 24 + n] = a2[nt][r] + bv;
                    }
                }
            }
            __syncthreads();
            if (tid < 16) {
                float v[NCLS];
                float mx = -3.4e38f;
#pragma unroll
                for (int c = 0; c < NCLS; ++c) { v[c] = lg[tid * 24 + c]; mx = fmaxf(mx, v[c]); }
                float s = 0.f;
#pragma unroll
                for (int c = 0; c < NCLS; ++c) s += __expf(v[c] - mx);
                float lse = mx + __logf(s);
                float* orow = out + ((size_t)(B0 + tid) * S_LEN + t) * NCLS;
#pragma unroll
                for (int c = 0; c < NCLS; ++c) orow[c] = v[c] - lse;
            }
        }
    }
}

extern "C" void kernel_launch(void* const* d_in, const int* in_sizes, int n_in,
                              void* d_out, int out_size, void* d_ws, size_t ws_size,
                              hipStream_t stream) {
    const float* x    = (const float*)d_in[0];
    const float* w_ih = (const float*)d_in[1];
    const float* w_hh = (const float*)d_in[2];
    const float* b_ih = (const float*)d_in[3];
    const float* b_hh = (const float*)d_in[4];
    const float* w1   = (const float*)d_in[5];
    const float* b1   = (const float*)d_in[6];
    const float* w2   = (const float*)d_in[7];
    const float* b2   = (const float*)d_in[8];

    // d_ws: hb 4 MB | ctr 32 KB | done 4 KB | w1b 256 KB | w2b 10 KB (~4.3 MB)
    char* ws = (char*)d_ws;
    unsigned short* hb   = (unsigned short*)ws;                   // 16*16*16*512 bf16
    unsigned*       ctr  = (unsigned*)(ws + 4194304);
    unsigned*       done = (unsigned*)(ws + 4194304 + 32768);
    unsigned short* w1b  = (unsigned short*)(ws + 4194304 + 32768 + 4096);
    unsigned short* w2b  = (unsigned short*)(ws + 4194304 + 32768 + 4096 + 262144);

    prep_kernel<<<512, 256, 0, stream>>>(w1, w2, w1b, w2b, ctr);
    lstm_fused_kernel<<<320, 256, 0, stream>>>(x, w_ih, w_hh, b_ih, b_hh,
                                               w1b, b1, w2b, b2,
                                               (float*)d_out, hb, ctr, done);
}

// Round 6
// 2562.577 us; speedup vs baseline: 3.7677x; 1.1304x over previous
//
#include <hip/hip_runtime.h>

#define S_LEN 512
#define HID   512
#define FEAT  26
#define NCLS  20
#define DRING 16

typedef short bf16x8 __attribute__((ext_vector_type(8)));
typedef float f32x4  __attribute__((ext_vector_type(4)));

__device__ __forceinline__ unsigned short f2bf(float f) {   // RNE
    unsigned u = __builtin_bit_cast(unsigned, f);
    unsigned r = (u + 0x7FFFu + ((u >> 16) & 1u)) >> 16;
    return (unsigned short)r;
}
__device__ __forceinline__ float sigm(float x) { return 1.f / (1.f + __expf(-x)); }
__device__ __forceinline__ float tanh_f(float x) {
    float xc = fminf(fmaxf(x, -15.f), 15.f);
    float t = __expf(-2.f * xc);
    return (1.f - t) / (1.f + t);
}

// 4 coherent (MALL, bypass L1/L2) 16B loads + drain.
__device__ __forceinline__ void load4_coherent(const unsigned short* p,
                                               uint4& a0, uint4& a1, uint4& a2, uint4& a3) {
    asm volatile(
        "global_load_dwordx4 %0, %4, off sc0 sc1\n\t"
        "global_load_dwordx4 %1, %5, off sc0 sc1\n\t"
        "global_load_dwordx4 %2, %6, off sc0 sc1\n\t"
        "global_load_dwordx4 %3, %7, off sc0 sc1\n\t"
        "s_waitcnt vmcnt(0)"
        : "=&v"(a0), "=&v"(a1), "=&v"(a2), "=&v"(a3)
        : "v"(p), "v"(p + 8), "v"(p + 16), "v"(p + 24)
        : "memory");
}
// coherent dword store + drain (h data: must be at MALL before flag).
__device__ __forceinline__ void store_coherent(unsigned short* p, unsigned d) {
    asm volatile(
        "global_store_dword %0, %1, off sc0 sc1\n\t"
        "s_waitcnt vmcnt(0)"
        :: "v"(p), "v"(d) : "memory");
}
// coherent dword store, no drain (flag/done publish — fire and forget).
__device__ __forceinline__ void store_u32_nowait(unsigned* p, unsigned d) {
    asm volatile("global_store_dword %0, %1, off sc0 sc1" :: "v"(p), "v"(d) : "memory");
}
// coherent dword load (poll).
__device__ __forceinline__ unsigned load_u32_coherent(const unsigned* p) {
    unsigned v;
    asm volatile("global_load_dword %0, %1, off sc0 sc1\n\ts_waitcnt vmcnt(0)"
                 : "=v"(v) : "v"(p) : "memory");
    return v;
}

// zero flags+done, convert w1/w2 fp32 -> bf16
__global__ void prep_kernel(const float* __restrict__ w1, const float* __restrict__ w2,
                            unsigned short* __restrict__ w1b, unsigned short* __restrict__ w2b,
                            unsigned* __restrict__ flagsdone) {
    int i = blockIdx.x * 256 + threadIdx.x;
    if (i < 6144) flagsdone[i] = 0u;          // flags 4096 + done 2048 dwords
    if (i < 256 * 512) w1b[i] = f2bf(w1[i]);
    if (i < NCLS * 256) w2b[i] = f2bf(w2[i]);
}

// 384 wgs: wg<256 LSTM (16 clusters x 16 wgs), wg>=256 MLP (16 clusters x 8 wgs).
// Sync: per-producer 64B-padded epoch flags, sc0sc1 everywhere; wave0 lanes0-15
// poll the 16 flags (ballot exit), waves1-3 spin on an LDS epoch word.
__global__ __launch_bounds__(256, 2) void lstm_fused_kernel(
    const float* __restrict__ x,      // [B][S][FEAT] fp32
    const float* __restrict__ w_ih,   // [2048][FEAT] fp32
    const float* __restrict__ w_hh,   // [2048][HID] fp32
    const float* __restrict__ b_ih,
    const float* __restrict__ b_hh,
    const unsigned short* __restrict__ w1b,  // [256][512] bf16
    const float* __restrict__ b1,
    const unsigned short* __restrict__ w2b,  // [20][256] bf16
    const float* __restrict__ b2,
    float* __restrict__ out,          // [B][S][NCLS] fp32
    unsigned short* __restrict__ hb,  // [16][DRING][16][HID] bf16 ring
    unsigned* __restrict__ flags,     // [16][16] x 16-dword stride: producer epochs
    unsigned* __restrict__ done)      // [16][8] x 16-dword stride: MLP progress
{
    const int tid  = threadIdx.x;
    const int wave = tid >> 6;
    const int lane = tid & 63;
    const int quad = lane >> 4;
    const int l16  = lane & 15;
    const int wg   = blockIdx.x;

    __shared__ __align__(16) unsigned short At[16 * 552];
    __shared__ float zb[16 * 132];
    __shared__ __align__(16) unsigned short hid[16 * 264];
    __shared__ float lg[16 * 24];
    __shared__ unsigned rdy;

    if (tid == 0) rdy = 0u;
    __syncthreads();

    if (wg < 256) {
        // ======================= LSTM role =======================
        const int clust = (wg & 7) * 2 + (wg >= 128 ? 1 : 0);
        const int wic   = (wg >> 3) & 15;
        const int B0    = clust * 16;
        const int U0    = wic * 32;

        bf16x8 bB[2][17];           // kk 0..15 = w_hh, kk 16 = w_ih
#pragma unroll
        for (int tl = 0; tl < 2; ++tl) {
            const int row = wave * 512 + U0 + tl * 16 + l16;
            const float* wrow = w_hh + (size_t)row * HID;
#pragma unroll
            for (int kk = 0; kk < 16; ++kk) {
                const float* p = wrow + kk * 32 + quad * 8;
                bf16x8 v;
#pragma unroll
                for (int j = 0; j < 8; ++j) v[j] = (short)f2bf(p[j]);
                bB[tl][kk] = v;
            }
            const float* irow = w_ih + (size_t)row * FEAT;
            bf16x8 v;
#pragma unroll
            for (int j = 0; j < 8; ++j) {
                int ftr = quad * 8 + j;
                v[j] = (ftr < FEAT) ? (short)f2bf(irow[ftr]) : (short)0;
            }
            bB[tl][16] = v;
        }

        const int gb = tid >> 4;
        const int gu = tid & 15;
        float bias[2][4];
#pragma unroll
        for (int uu = 0; uu < 2; ++uu)
#pragma unroll
            for (int g = 0; g < 4; ++g) {
                int r = g * 512 + U0 + 2 * gu + uu;
                bias[uu][g] = b_ih[r] + b_hh[r];
            }
        float cst[2] = {0.f, 0.f};

        const int sm = tid >> 4;
        const int sc = tid & 15;
        unsigned short* hbc = hb + (size_t)clust * DRING * 16 * HID;
        unsigned* myflag = flags + (clust * 16 + wic) * 16;
        const unsigned* peer = flags + (clust * 16 + (lane & 15)) * 16;

        for (int t = 0; t < S_LEN; ++t) {
            // stage x_t (independent of h; load overlaps flag wait)
            {
                unsigned pk = 0u;
                if (sc <= 12) {
                    float2 xv = *(const float2*)(x + ((size_t)(B0 + sm) * S_LEN + t) * FEAT + sc * 2);
                    pk = (unsigned)f2bf(xv.x) | ((unsigned)f2bf(xv.y) << 16);
                }
                *(unsigned*)(At + sm * 552 + 512 + sc * 2) = pk;
            }
            if (t > 0) {
                if (wave == 0) {
                    if (t >= DRING && lane == 0) {    // backpressure (rarely binds)
                        const unsigned* dn = done + (clust * 8 + (t & 7)) * 16;
                        while (load_u32_coherent(dn) < (unsigned)(t - (DRING - 1)))
                            __builtin_amdgcn_s_sleep(8);
                    }
                    for (;;) {                         // lanes poll all 16 producer flags
                        unsigned v = load_u32_coherent(peer);
                        if (__ballot(v >= (unsigned)t) == ~0ull) break;
                        __builtin_amdgcn_s_sleep(1);
                    }
                    if (lane == 0)
                        __hip_atomic_store(&rdy, (unsigned)t, __ATOMIC_RELAXED,
                                           __HIP_MEMORY_SCOPE_WORKGROUP);
                } else {
                    while (__hip_atomic_load(&rdy, __ATOMIC_RELAXED,
                                             __HIP_MEMORY_SCOPE_WORKGROUP) < (unsigned)t)
                        __builtin_amdgcn_s_sleep(1);
                }
                // stage h_{t-1} from ring slot (t-1)&15
                const unsigned short* src =
                    hbc + ((t - 1) & (DRING - 1)) * 16 * HID + sm * HID + sc * 32;
                unsigned short* dst = At + sm * 552 + sc * 32;
                uint4 a0, a1, a2, a3;
                load4_coherent(src, a0, a1, a2, a3);
                *(uint4*)(dst)      = a0;
                *(uint4*)(dst + 8)  = a1;
                *(uint4*)(dst + 16) = a2;
                *(uint4*)(dst + 24) = a3;
            }
            __syncthreads();

            f32x4 acc0 = {0.f, 0.f, 0.f, 0.f};
            f32x4 acc1 = {0.f, 0.f, 0.f, 0.f};
            const unsigned short* arow = At + l16 * 552 + quad * 8;
            if (t > 0) {
#pragma unroll
                for (int kk = 0; kk < 17; ++kk) {
                    bf16x8 a = __builtin_bit_cast(bf16x8, *(const uint4*)(arow + kk * 32));
                    acc0 = __builtin_amdgcn_mfma_f32_16x16x32_bf16(a, bB[0][kk], acc0, 0, 0, 0);
                    acc1 = __builtin_amdgcn_mfma_f32_16x16x32_bf16(a, bB[1][kk], acc1, 0, 0, 0);
                }
            } else {
                bf16x8 a = __builtin_bit_cast(bf16x8, *(const uint4*)(arow + 16 * 32));
                acc0 = __builtin_amdgcn_mfma_f32_16x16x32_bf16(a, bB[0][16], acc0, 0, 0, 0);
                acc1 = __builtin_amdgcn_mfma_f32_16x16x32_bf16(a, bB[1][16], acc1, 0, 0, 0);
            }
#pragma unroll
            for (int r = 0; r < 4; ++r) {
                zb[(quad * 4 + r) * 132 + wave * 32 + l16]      = acc0[r];
                zb[(quad * 4 + r) * 132 + wave * 32 + 16 + l16] = acc1[r];
            }
            __syncthreads();

            {   // gates -> packed coherent store into ring slot t&15
                const float* zrow = zb + gb * 132;
                unsigned short hv2[2];
#pragma unroll
                for (int uu = 0; uu < 2; ++uu) {
                    int u = 2 * gu + uu;
                    float zi = zrow[u]      + bias[uu][0];
                    float zf = zrow[32 + u] + bias[uu][1];
                    float zg = zrow[64 + u] + bias[uu][2];
                    float zo = zrow[96 + u] + bias[uu][3];
                    float cn = sigm(zf) * cst[uu] + sigm(zi) * tanh_f(zg);
                    cst[uu] = cn;
                    hv2[uu] = f2bf(sigm(zo) * tanh_f(cn));
                }
                unsigned short* hp =
                    hbc + (t & (DRING - 1)) * 16 * HID + gb * HID + U0 + 2 * gu;
                store_coherent(hp, (unsigned)hv2[0] | ((unsigned)hv2[1] << 16));
            }
            __syncthreads();             // all h stores at MALL before flag
            if (tid == 0) store_u32_nowait(myflag, (unsigned)(t + 1));
        }
    } else {
        // ======================= MLP role =======================
        const int mwg  = wg - 256;
        const int mc   = mwg >> 3;      // cluster
        const int m    = mwg & 7;       // phase: steps t == m (mod 8)
        const int B0   = mc * 16;
        unsigned* mydone = done + (mc * 8 + m) * 16;
        const unsigned* peer = flags + (mc * 16 + (lane & 15)) * 16;
        const unsigned short* hbc = hb + (size_t)mc * DRING * 16 * HID;
        const int sm = tid >> 4;
        const int sc = tid & 15;

        for (int t = m; t < S_LEN; t += 8) {
            if (wave == 0) {
                for (;;) {
                    unsigned v = load_u32_coherent(peer);
                    if (__ballot(v >= (unsigned)(t + 1)) == ~0ull) break;
                    __builtin_amdgcn_s_sleep(8);
                }
                if (lane == 0)
                    __hip_atomic_store(&rdy, (unsigned)(t + 1), __ATOMIC_RELAXED,
                                       __HIP_MEMORY_SCOPE_WORKGROUP);
            } else {
                while (__hip_atomic_load(&rdy, __ATOMIC_RELAXED,
                                         __HIP_MEMORY_SCOPE_WORKGROUP) < (unsigned)(t + 1))
                    __builtin_amdgcn_s_sleep(8);
            }
            {   // stage h_t from ring slot t&15
                const unsigned short* src =
                    hbc + (t & (DRING - 1)) * 16 * HID + sm * HID + sc * 32;
                unsigned short* dst = At + sm * 552 + sc * 32;
                uint4 a0, a1, a2, a3;
                load4_coherent(src, a0, a1, a2, a3);
                *(uint4*)(dst)      = a0;
                *(uint4*)(dst + 8)  = a1;
                *(uint4*)(dst + 16) = a2;
                *(uint4*)(dst + 24) = a3;
            }
            __syncthreads();
            if (tid == 0) store_u32_nowait(mydone, (unsigned)(t + 1));  // slot consumed

            // GEMM1: [16 x 512] @ [512 x 256]
            f32x4 a1[4];
#pragma unroll
            for (int nt = 0; nt < 4; ++nt) a1[nt] = (f32x4){0.f, 0.f, 0.f, 0.f};
#pragma unroll
            for (int kk = 0; kk < 16; ++kk) {
                bf16x8 a = __builtin_bit_cast(
                    bf16x8, *(const uint4*)(At + l16 * 552 + kk * 32 + quad * 8));
#pragma unroll
                for (int nt = 0; nt < 4; ++nt) {
                    int n = wave * 64 + nt * 16 + l16;
                    bf16x8 b = __builtin_bit_cast(
                        bf16x8, *(const uint4*)(w1b + (size_t)n * 512 + kk * 32 + quad * 8));
                    a1[nt] = __builtin_amdgcn_mfma_f32_16x16x32_bf16(a, b, a1[nt], 0, 0, 0);
                }
            }
#pragma unroll
            for (int nt = 0; nt < 4; ++nt) {
                int n = wave * 64 + nt * 16 + l16;
                float bv = b1[n];
#pragma unroll
                for (int r = 0; r < 4; ++r) {
                    int mm = quad * 4 + r;
                    hid[mm * 264 + n] = f2bf(fmaxf(a1[nt][r] + bv, 0.f));
                }
            }
            __syncthreads();
            if (wave == 0) {   // GEMM2: [16 x 256] @ [256 x 20(pad32)]
                f32x4 a2[2];
                a2[0] = (f32x4){0.f, 0.f, 0.f, 0.f};
                a2[1] = (f32x4){0.f, 0.f, 0.f, 0.f};
#pragma unroll
                for (int kk = 0; kk < 8; ++kk) {
                    bf16x8 a = __builtin_bit_cast(
                        bf16x8, *(const uint4*)(hid + l16 * 264 + kk * 32 + quad * 8));
#pragma unroll
                    for (int nt = 0; nt < 2; ++nt) {
                        int n = nt * 16 + l16;
                        bf16x8 b;
                        if (n < NCLS) {
                            b = __builtin_bit_cast(
                                bf16x8, *(const uint4*)(w2b + (size_t)n * 256 + kk * 32 + quad * 8));
                        } else {
                            uint4 z; z.x = z.y = z.z = z.w = 0u;
                            b = __builtin_bit_cast(bf16x8, z);
                        }
                        a2[nt] = __builtin_amdgcn_mfma_f32_16x16x32_bf16(a, b, a2[nt], 0, 0, 0);
                    }
                }
#pragma unroll
                for (int nt = 0; nt < 2; ++nt) {
                    int n = nt * 16 + l16;
                    if (n < NCLS) {
                        float bv = b2[n];
#pragma unroll
                        for (int r = 0; r < 4; ++r)
                            lg[(quad * 4 + r) * 24 + n] = a2[nt][r] + bv;
                    }
                }
            }
            __syncthreads();
            if (tid < 16) {
                float v[NCLS];
                float mx = -3.4e38f;
#pragma unroll
                for (int c = 0; c < NCLS; ++c) { v[c] = lg[tid * 24 + c]; mx = fmaxf(mx, v[c]); }
                float s = 0.f;
#pragma unroll
                for (int c = 0; c < NCLS; ++c) s += __expf(v[c] - mx);
                float lse = mx + __logf(s);
                float* orow = out + ((size_t)(B0 + tid) * S_LEN + t) * NCLS;
#pragma unroll
                for (int c = 0; c < NCLS; ++c) orow[c] = v[c] - lse;
            }
        }
    }
}

extern "C" void kernel_launch(void* const* d_in, const int* in_sizes, int n_in,
                              void* d_out, int out_size, void* d_ws, size_t ws_size,
                              hipStream_t stream) {
    const float* x    = (const float*)d_in[0];
    const float* w_ih = (const float*)d_in[1];
    const float* w_hh = (const float*)d_in[2];
    const float* b_ih = (const float*)d_in[3];
    const float* b_hh = (const float*)d_in[4];
    const float* w1   = (const float*)d_in[5];
    const float* b1   = (const float*)d_in[6];
    const float* w2   = (const float*)d_in[7];
    const float* b2   = (const float*)d_in[8];

    // d_ws: hb 4MB | flags 16KB | done 8KB | w1b 256KB | w2b 10KB
    char* ws = (char*)d_ws;
    unsigned short* hb    = (unsigned short*)ws;
    unsigned*       flags = (unsigned*)(ws + 4194304);
    unsigned*       done  = (unsigned*)(ws + 4194304 + 16384);
    unsigned short* w1b   = (unsigned short*)(ws + 4194304 + 16384 + 8192);
    unsigned short* w2b   = (unsigned short*)(ws + 4194304 + 16384 + 8192 + 262144);

    prep_kernel<<<512, 256, 0, stream>>>(w1, w2, w1b, w2b, flags);
    lstm_fused_kernel<<<384, 256, 0, stream>>>(x, w_ih, w_hh, b_ih, b_hh,
                                               w1b, b1, w2b, b2,
                                               (float*)d_out, hb, flags, done);
}

// Round 7
// 2102.911 us; speedup vs baseline: 4.5913x; 1.2186x over previous
//
#include <hip/hip_runtime.h>

#define S_LEN 512
#define HID   512
#define FEAT  26
#define NCLS  20
#define DRING 16

typedef short bf16x8 __attribute__((ext_vector_type(8)));
typedef float f32x4  __attribute__((ext_vector_type(4)));

__device__ __forceinline__ unsigned short f2bf(float f) {   // RNE
    unsigned u = __builtin_bit_cast(unsigned, f);
    unsigned r = (u + 0x7FFFu + ((u >> 16) & 1u)) >> 16;
    return (unsigned short)r;
}
__device__ __forceinline__ float sigm(float x) { return 1.f / (1.f + __expf(-x)); }
__device__ __forceinline__ float tanh_f(float x) {
    float xc = fminf(fmaxf(x, -15.f), 15.f);
    float t = __expf(-2.f * xc);
    return (1.f - t) / (1.f + t);
}

// 4 coherent (MALL, bypass L1/L2) 16B loads + drain.
__device__ __forceinline__ void load4_coherent(const unsigned short* p,
                                               uint4& a0, uint4& a1, uint4& a2, uint4& a3) {
    asm volatile(
        "global_load_dwordx4 %0, %4, off sc0 sc1\n\t"
        "global_load_dwordx4 %1, %5, off sc0 sc1\n\t"
        "global_load_dwordx4 %2, %6, off sc0 sc1\n\t"
        "global_load_dwordx4 %3, %7, off sc0 sc1\n\t"
        "s_waitcnt vmcnt(0)"
        : "=&v"(a0), "=&v"(a1), "=&v"(a2), "=&v"(a3)
        : "v"(p), "v"(p + 8), "v"(p + 16), "v"(p + 24)
        : "memory");
}
// coherent dword store + drain.
__device__ __forceinline__ void store_coherent(unsigned short* p, unsigned d) {
    asm volatile(
        "global_store_dword %0, %1, off sc0 sc1\n\t"
        "s_waitcnt vmcnt(0)"
        :: "v"(p), "v"(d) : "memory");
}
// coherent dwordx2 store + drain.
__device__ __forceinline__ void store_coherent_x2(unsigned short* p, unsigned long long d) {
    asm volatile(
        "global_store_dwordx2 %0, %1, off sc0 sc1\n\t"
        "s_waitcnt vmcnt(0)"
        :: "v"(p), "v"(d) : "memory");
}
// coherent dword store, no drain (flag publish).
__device__ __forceinline__ void store_u32_nowait(unsigned* p, unsigned d) {
    asm volatile("global_store_dword %0, %1, off sc0 sc1" :: "v"(p), "v"(d) : "memory");
}
// coherent dword load (poll).
__device__ __forceinline__ unsigned load_u32_coherent(const unsigned* p) {
    unsigned v;
    asm volatile("global_load_dword %0, %1, off sc0 sc1\n\ts_waitcnt vmcnt(0)"
                 : "=v"(v) : "v"(p) : "memory");
    return v;
}

// zero sync words, convert w1/w2 fp32 -> bf16
__global__ void prep_kernel(const float* __restrict__ w1, const float* __restrict__ w2,
                            unsigned short* __restrict__ w1b, unsigned short* __restrict__ w2b,
                            unsigned* __restrict__ syncw, int nclear) {
    int i = blockIdx.x * 256 + threadIdx.x;
    if (i < nclear) syncw[i] = 0u;
    if (i < 256 * 512) w1b[i] = f2bf(w1[i]);
    if (i < NCLS * 256) w2b[i] = f2bf(w2[i]);
}

// ============================================================================
// BIG-WS PATH: 256 wgs on 256 CUs (1 wg/CU via launch_bounds(256,1) + ~340 VGPR).
// wg<128: LSTM, 16 clusters x 8 wgs, 64 units/wg, bB[4][17] register-resident.
// wg>=128: MLP, 16 clusters x 8 phases. h stored to full hs[16][512][16][512]
// (no ring wrap -> no backpressure -> deadlock-free regardless of residency).
// ============================================================================
__global__ __launch_bounds__(256, 1) void lstm_big_kernel(
    const float* __restrict__ x,
    const float* __restrict__ w_ih,
    const float* __restrict__ w_hh,
    const float* __restrict__ b_ih,
    const float* __restrict__ b_hh,
    const unsigned short* __restrict__ w1b,
    const float* __restrict__ b1,
    const unsigned short* __restrict__ w2b,
    const float* __restrict__ b2,
    float* __restrict__ out,
    unsigned short* __restrict__ hs,   // [16][S][16][HID] bf16
    unsigned* __restrict__ flags)      // [16][8] x 16-dword stride
{
    const int tid  = threadIdx.x;
    const int wave = tid >> 6;
    const int lane = tid & 63;
    const int quad = lane >> 4;
    const int l16  = lane & 15;
    const int wg   = blockIdx.x;

    __shared__ __align__(16) unsigned short At[16 * 552];
    __shared__ float zb[16 * 260];
    __shared__ __align__(16) unsigned short hid[16 * 264];
    __shared__ float lg[16 * 24];
    __shared__ unsigned rdy;
    if (tid == 0) rdy = 0u;
    __syncthreads();

    if (wg < 128) {
        // =============== LSTM role ===============
        const int clust = wg >> 3;
        const int wic   = wg & 7;
        const int B0    = clust * 16;
        const int U0    = wic * 64;

        bf16x8 bB[4][17];           // kk 0..15 = w_hh, kk 16 = w_ih
#pragma unroll
        for (int tl = 0; tl < 4; ++tl) {
            const int row = wave * 512 + U0 + tl * 16 + l16;
            const float* wrow = w_hh + (size_t)row * HID;
#pragma unroll
            for (int kk = 0; kk < 16; ++kk) {
                const float* p = wrow + kk * 32 + quad * 8;
                bf16x8 v;
#pragma unroll
                for (int j = 0; j < 8; ++j) v[j] = (short)f2bf(p[j]);
                bB[tl][kk] = v;
            }
            const float* irow = w_ih + (size_t)row * FEAT;
            bf16x8 v;
#pragma unroll
            for (int j = 0; j < 8; ++j) {
                int ftr = quad * 8 + j;
                v[j] = (ftr < FEAT) ? (short)f2bf(irow[ftr]) : (short)0;
            }
            bB[tl][16] = v;
        }

        const int gb = tid >> 4;
        const int gu = tid & 15;     // units 4gu..4gu+3
        float bias[4][4];
#pragma unroll
        for (int uu = 0; uu < 4; ++uu)
#pragma unroll
            for (int g = 0; g < 4; ++g) {
                int r = g * 512 + U0 + 4 * gu + uu;
                bias[uu][g] = b_ih[r] + b_hh[r];
            }
        float cst[4] = {0.f, 0.f, 0.f, 0.f};

        const int sm = tid >> 4;
        const int sc = tid & 15;
        unsigned short* hsc = hs + (size_t)clust * S_LEN * 16 * HID;
        unsigned* myflag = flags + (clust * 8 + wic) * 16;
        const unsigned* peer = flags + (clust * 8 + (lane & 7)) * 16;

        for (int t = 0; t < S_LEN; ++t) {
            {   // stage x_t (overlaps wait)
                unsigned pk = 0u;
                if (sc <= 12) {
                    float2 xv = *(const float2*)(x + ((size_t)(B0 + sm) * S_LEN + t) * FEAT + sc * 2);
                    pk = (unsigned)f2bf(xv.x) | ((unsigned)f2bf(xv.y) << 16);
                }
                *(unsigned*)(At + sm * 552 + 512 + sc * 2) = pk;
            }
            if (t > 0) {
                if (wave == 0) {
                    for (;;) {
                        unsigned v = load_u32_coherent(peer);
                        if (__ballot(v >= (unsigned)t) == ~0ull) break;
                        __builtin_amdgcn_s_sleep(1);
                    }
                    if (lane == 0)
                        __hip_atomic_store(&rdy, (unsigned)t, __ATOMIC_RELAXED,
                                           __HIP_MEMORY_SCOPE_WORKGROUP);
                } else {
                    while (__hip_atomic_load(&rdy, __ATOMIC_RELAXED,
                                             __HIP_MEMORY_SCOPE_WORKGROUP) < (unsigned)t)
                        __builtin_amdgcn_s_sleep(1);
                }
                const unsigned short* src =
                    hsc + ((size_t)(t - 1) * 16 + sm) * HID + sc * 32;
                unsigned short* dst = At + sm * 552 + sc * 32;
                uint4 a0, a1, a2, a3;
                load4_coherent(src, a0, a1, a2, a3);
                *(uint4*)(dst)      = a0;
                *(uint4*)(dst + 8)  = a1;
                *(uint4*)(dst + 16) = a2;
                *(uint4*)(dst + 24) = a3;
            }
            __syncthreads();

            f32x4 acc[4];
#pragma unroll
            for (int tl = 0; tl < 4; ++tl) acc[tl] = (f32x4){0.f, 0.f, 0.f, 0.f};
            const unsigned short* arow = At + l16 * 552 + quad * 8;
            if (t > 0) {
#pragma unroll
                for (int kk = 0; kk < 17; ++kk) {
                    bf16x8 a = __builtin_bit_cast(bf16x8, *(const uint4*)(arow + kk * 32));
#pragma unroll
                    for (int tl = 0; tl < 4; ++tl)
                        acc[tl] = __builtin_amdgcn_mfma_f32_16x16x32_bf16(a, bB[tl][kk], acc[tl], 0, 0, 0);
                }
            } else {
                bf16x8 a = __builtin_bit_cast(bf16x8, *(const uint4*)(arow + 16 * 32));
#pragma unroll
                for (int tl = 0; tl < 4; ++tl)
                    acc[tl] = __builtin_amdgcn_mfma_f32_16x16x32_bf16(a, bB[tl][16], acc[tl], 0, 0, 0);
            }
#pragma unroll
            for (int tl = 0; tl < 4; ++tl)
#pragma unroll
                for (int r = 0; r < 4; ++r)
                    zb[(quad * 4 + r) * 260 + wave * 64 + tl * 16 + l16] = acc[tl][r];
            __syncthreads();

            {   // gates: 4 units -> one packed 8B coherent store
                const float* zrow = zb + gb * 260;
                unsigned short hv[4];
#pragma unroll
                for (int uu = 0; uu < 4; ++uu) {
                    int u = 4 * gu + uu;
                    float zi = zrow[u]       + bias[uu][0];
                    float zf = zrow[64 + u]  + bias[uu][1];
                    float zg = zrow[128 + u] + bias[uu][2];
                    float zo = zrow[192 + u] + bias[uu][3];
                    float cn = sigm(zf) * cst[uu] + sigm(zi) * tanh_f(zg);
                    cst[uu] = cn;
                    hv[uu] = f2bf(sigm(zo) * tanh_f(cn));
                }
                unsigned long long d = (unsigned long long)hv[0]
                                     | ((unsigned long long)hv[1] << 16)
                                     | ((unsigned long long)hv[2] << 32)
                                     | ((unsigned long long)hv[3] << 48);
                unsigned short* hp = hsc + ((size_t)t * 16 + gb) * HID + U0 + 4 * gu;
                store_coherent_x2(hp, d);
            }
            __syncthreads();             // all h stores at MALL before flag
            if (tid == 0) store_u32_nowait(myflag, (unsigned)(t + 1));
        }
    } else {
        // =============== MLP role ===============
        const int mwg  = wg - 128;
        const int mc   = mwg >> 3;
        const int m    = mwg & 7;
        const int B0   = mc * 16;
        const unsigned* peer = flags + (mc * 8 + (lane & 7)) * 16;
        const unsigned short* hsc = hs + (size_t)mc * S_LEN * 16 * HID;
        const int sm = tid >> 4;
        const int sc = tid & 15;

        for (int t = m; t < S_LEN; t += 8) {
            if (wave == 0) {
                for (;;) {
                    unsigned v = load_u32_coherent(peer);
                    if (__ballot(v >= (unsigned)(t + 1)) == ~0ull) break;
                    __builtin_amdgcn_s_sleep(8);
                }
                if (lane == 0)
                    __hip_atomic_store(&rdy, (unsigned)(t + 1), __ATOMIC_RELAXED,
                                       __HIP_MEMORY_SCOPE_WORKGROUP);
            } else {
                while (__hip_atomic_load(&rdy, __ATOMIC_RELAXED,
                                         __HIP_MEMORY_SCOPE_WORKGROUP) < (unsigned)(t + 1))
                    __builtin_amdgcn_s_sleep(8);
            }
            {
                const unsigned short* src = hsc + ((size_t)t * 16 + sm) * HID + sc * 32;
                unsigned short* dst = At + sm * 552 + sc * 32;
                uint4 a0, a1, a2, a3;
                load4_coherent(src, a0, a1, a2, a3);
                *(uint4*)(dst)      = a0;
                *(uint4*)(dst + 8)  = a1;
                *(uint4*)(dst + 16) = a2;
                *(uint4*)(dst + 24) = a3;
            }
            __syncthreads();

            f32x4 a1[4];
#pragma unroll
            for (int nt = 0; nt < 4; ++nt) a1[nt] = (f32x4){0.f, 0.f, 0.f, 0.f};
#pragma unroll
            for (int kk = 0; kk < 16; ++kk) {
                bf16x8 a = __builtin_bit_cast(
                    bf16x8, *(const uint4*)(At + l16 * 552 + kk * 32 + quad * 8));
#pragma unroll
                for (int nt = 0; nt < 4; ++nt) {
                    int n = wave * 64 + nt * 16 + l16;
                    bf16x8 b = __builtin_bit_cast(
                        bf16x8, *(const uint4*)(w1b + (size_t)n * 512 + kk * 32 + quad * 8));
                    a1[nt] = __builtin_amdgcn_mfma_f32_16x16x32_bf16(a, b, a1[nt], 0, 0, 0);
                }
            }
#pragma unroll
            for (int nt = 0; nt < 4; ++nt) {
                int n = wave * 64 + nt * 16 + l16;
                float bv = b1[n];
#pragma unroll
                for (int r = 0; r < 4; ++r)
                    hid[(quad * 4 + r) * 264 + n] = f2bf(fmaxf(a1[nt][r] + bv, 0.f));
            }
            __syncthreads();
            if (wave == 0) {
                f32x4 a2[2];
                a2[0] = (f32x4){0.f, 0.f, 0.f, 0.f};
                a2[1] = (f32x4){0.f, 0.f, 0.f, 0.f};
#pragma unroll
                for (int kk = 0; kk < 8; ++kk) {
                    bf16x8 a = __builtin_bit_cast(
                        bf16x8, *(const uint4*)(hid + l16 * 264 + kk * 32 + quad * 8));
#pragma unroll
                    for (int nt = 0; nt < 2; ++nt) {
                        int n = nt * 16 + l16;
                        bf16x8 b;
                        if (n < NCLS) {
                            b = __builtin_bit_cast(
                                bf16x8, *(const uint4*)(w2b + (size_t)n * 256 + kk * 32 + quad * 8));
                        } else {
                            uint4 z; z.x = z.y = z.z = z.w = 0u;
                            b = __builtin_bit_cast(bf16x8, z);
                        }
                        a2[nt] = __builtin_amdgcn_mfma_f32_16x16x32_bf16(a, b, a2[nt], 0, 0, 0);
                    }
                }
#pragma unroll
                for (int nt = 0; nt < 2; ++nt) {
                    int n = nt * 16 + l16;
                    if (n < NCLS) {
                        float bv = b2[n];
#pragma unroll
                        for (int r = 0; r < 4; ++r)
                            lg[(quad * 4 + r) * 24 + n] = a2[nt][r] + bv;
                    }
                }
            }
            __syncthreads();
            if (tid < 16) {
                float v[NCLS];
                float mx = -3.4e38f;
#pragma unroll
                for (int c = 0; c < NCLS; ++c) { v[c] = lg[tid * 24 + c]; mx = fmaxf(mx, v[c]); }
                float s = 0.f;
#pragma unroll
                for (int c = 0; c < NCLS; ++c) s += __expf(v[c] - mx);
                float lse = mx + __logf(s);
                float* orow = out + ((size_t)(B0 + tid) * S_LEN + t) * NCLS;
#pragma unroll
                for (int c = 0; c < NCLS; ++c) orow[c] = v[c] - lse;
            }
            __syncthreads();
        }
    }
}

// ============================================================================
// FALLBACK (small ws): round-6 kernel verbatim. 384 wgs, 16x16 LSTM + 16x8 MLP,
// 16-slot ring + done backpressure.
// ============================================================================
__global__ __launch_bounds__(256, 2) void lstm_fused_kernel(
    const float* __restrict__ x, const float* __restrict__ w_ih,
    const float* __restrict__ w_hh, const float* __restrict__ b_ih,
    const float* __restrict__ b_hh, const unsigned short* __restrict__ w1b,
    const float* __restrict__ b1, const unsigned short* __restrict__ w2b,
    const float* __restrict__ b2, float* __restrict__ out,
    unsigned short* __restrict__ hb, unsigned* __restrict__ flags,
    unsigned* __restrict__ done)
{
    const int tid  = threadIdx.x;
    const int wave = tid >> 6;
    const int lane = tid & 63;
    const int quad = lane >> 4;
    const int l16  = lane & 15;
    const int wg   = blockIdx.x;

    __shared__ __align__(16) unsigned short At[16 * 552];
    __shared__ float zb[16 * 132];
    __shared__ __align__(16) unsigned short hid[16 * 264];
    __shared__ float lg[16 * 24];
    __shared__ unsigned rdy;
    if (tid == 0) rdy = 0u;
    __syncthreads();

    if (wg < 256) {
        const int clust = (wg & 7) * 2 + (wg >= 128 ? 1 : 0);
        const int wic   = (wg >> 3) & 15;
        const int B0    = clust * 16;
        const int U0    = wic * 32;

        bf16x8 bB[2][17];
#pragma unroll
        for (int tl = 0; tl < 2; ++tl) {
            const int row = wave * 512 + U0 + tl * 16 + l16;
            const float* wrow = w_hh + (size_t)row * HID;
#pragma unroll
            for (int kk = 0; kk < 16; ++kk) {
                const float* p = wrow + kk * 32 + quad * 8;
                bf16x8 v;
#pragma unroll
                for (int j = 0; j < 8; ++j) v[j] = (short)f2bf(p[j]);
                bB[tl][kk] = v;
            }
            const float* irow = w_ih + (size_t)row * FEAT;
            bf16x8 v;
#pragma unroll
            for (int j = 0; j < 8; ++j) {
                int ftr = quad * 8 + j;
                v[j] = (ftr < FEAT) ? (short)f2bf(irow[ftr]) : (short)0;
            }
            bB[tl][16] = v;
        }

        const int gb = tid >> 4;
        const int gu = tid & 15;
        float bias[2][4];
#pragma unroll
        for (int uu = 0; uu < 2; ++uu)
#pragma unroll
            for (int g = 0; g < 4; ++g) {
                int r = g * 512 + U0 + 2 * gu + uu;
                bias[uu][g] = b_ih[r] + b_hh[r];
            }
        float cst[2] = {0.f, 0.f};

        const int sm = tid >> 4;
        const int sc = tid & 15;
        unsigned short* hbc = hb + (size_t)clust * DRING * 16 * HID;
        unsigned* myflag = flags + (clust * 16 + wic) * 16;
        const unsigned* peer = flags + (clust * 16 + (lane & 15)) * 16;

        for (int t = 0; t < S_LEN; ++t) {
            {
                unsigned pk = 0u;
                if (sc <= 12) {
                    float2 xv = *(const float2*)(x + ((size_t)(B0 + sm) * S_LEN + t) * FEAT + sc * 2);
                    pk = (unsigned)f2bf(xv.x) | ((unsigned)f2bf(xv.y) << 16);
                }
                *(unsigned*)(At + sm * 552 + 512 + sc * 2) = pk;
            }
            if (t > 0) {
                if (wave == 0) {
                    if (t >= DRING && lane == 0) {
                        const unsigned* dn = done + (clust * 8 + (t & 7)) * 16;
                        while (load_u32_coherent(dn) < (unsigned)(t - (DRING - 1)))
                            __builtin_amdgcn_s_sleep(8);
                    }
                    for (;;) {
                        unsigned v = load_u32_coherent(peer);
                        if (__ballot(v >= (unsigned)t) == ~0ull) break;
                        __builtin_amdgcn_s_sleep(1);
                    }
                    if (lane == 0)
                        __hip_atomic_store(&rdy, (unsigned)t, __ATOMIC_RELAXED,
                                           __HIP_MEMORY_SCOPE_WORKGROUP);
                } else {
                    while (__hip_atomic_load(&rdy, __ATOMIC_RELAXED,
                                             __HIP_MEMORY_SCOPE_WORKGROUP) < (unsigned)t)
                        __builtin_amdgcn_s_sleep(1);
                }
                const unsigned short* src =
                    hbc + ((t - 1) & (DRING - 1)) * 16 * HID + sm * HID + sc * 32;
                unsigned short* dst = At + sm * 552 + sc * 32;
                uint4 a0, a1, a2, a3;
                load4_coherent(src, a0, a1, a2, a3);
                *(uint4*)(dst)      = a0;
                *(uint4*)(dst + 8)  = a1;
                *(uint4*)(dst + 16) = a2;
                *(uint4*)(dst + 24) = a3;
            }
            __syncthreads();

            f32x4 acc0 = {0.f, 0.f, 0.f, 0.f};
            f32x4 acc1 = {0.f, 0.f, 0.f, 0.f};
            const unsigned short* arow = At + l16 * 552 + quad * 8;
            if (t > 0) {
#pragma unroll
                for (int kk = 0; kk < 17; ++kk) {
                    bf16x8 a = __builtin_bit_cast(bf16x8, *(const uint4*)(arow + kk * 32));
                    acc0 = __builtin_amdgcn_mfma_f32_16x16x32_bf16(a, bB[0][kk], acc0, 0, 0, 0);
                    acc1 = __builtin_amdgcn_mfma_f32_16x16x32_bf16(a, bB[1][kk], acc1, 0, 0, 0);
                }
            } else {
                bf16x8 a = __builtin_bit_cast(bf16x8, *(const uint4*)(arow + 16 * 32));
                acc0 = __builtin_amdgcn_mfma_f32_16x16x32_bf16(a, bB[0][16], acc0, 0, 0, 0);
                acc1 = __builtin_amdgcn_mfma_f32_16x16x32_bf16(a, bB[1][16], acc1, 0, 0, 0);
            }
#pragma unroll
            for (int r = 0; r < 4; ++r) {
                zb[(quad * 4 + r) * 132 + wave * 32 + l16]      = acc0[r];
                zb[(quad * 4 + r) * 132 + wave * 32 + 16 + l16] = acc1[r];
            }
            __syncthreads();

            {
                const float* zrow = zb + gb * 132;
                unsigned short hv2[2];
#pragma unroll
                for (int uu = 0; uu < 2; ++uu) {
                    int u = 2 * gu + uu;
                    float zi = zrow[u]      + bias[uu][0];
                    float zf = zrow[32 + u] + bias[uu][1];
                    float zg = zrow[64 + u] + bias[uu][2];
                    float zo = zrow[96 + u] + bias[uu][3];
                    float cn = sigm(zf) * cst[uu] + sigm(zi) * tanh_f(zg);
                    cst[uu] = cn;
                    hv2[uu] = f2bf(sigm(zo) * tanh_f(cn));
                }
                unsigned short* hp =
                    hbc + (t & (DRING - 1)) * 16 * HID + gb * HID + U0 + 2 * gu;
                store_coherent(hp, (unsigned)hv2[0] | ((unsigned)hv2[1] << 16));
            }
            __syncthreads();
            if (tid == 0) store_u32_nowait(myflag, (unsigned)(t + 1));
        }
    } else {
        const int mwg  = wg - 256;
        const int mc   = mwg >> 3;
        const int m    = mwg & 7;
        const int B0   = mc * 16;
        unsigned* mydone = done + (mc * 8 + m) * 16;
        const unsigned* peer = flags + (mc * 16 + (lane & 15)) * 16;
        const unsigned short* hbc = hb + (size_t)mc * DRING * 16 * HID;
        const int sm = tid >> 4;
        const int sc = tid & 15;

        for (int t = m; t < S_LEN; t += 8) {
            if (wave == 0) {
                for (;;) {
                    unsigned v = load_u32_coherent(peer);
                    if (__ballot(v >= (unsigned)(t + 1)) == ~0ull) break;
                    __builtin_amdgcn_s_sleep(8);
                }
                if (lane == 0)
                    __hip_atomic_store(&rdy, (unsigned)(t + 1), __ATOMIC_RELAXED,
                                       __HIP_MEMORY_SCOPE_WORKGROUP);
            } else {
                while (__hip_atomic_load(&rdy, __ATOMIC_RELAXED,
                                         __HIP_MEMORY_SCOPE_WORKGROUP) < (unsigned)(t + 1))
                    __builtin_amdgcn_s_sleep(8);
            }
            {
                const unsigned short* src =
                    hbc + (t & (DRING - 1)) * 16 * HID + sm * HID + sc * 32;
                unsigned short* dst = At + sm * 552 + sc * 32;
                uint4 a0, a1, a2, a3;
                load4_coherent(src, a0, a1, a2, a3);
                *(uint4*)(dst)      = a0;
                *(uint4*)(dst + 8)  = a1;
                *(uint4*)(dst + 16) = a2;
                *(uint4*)(dst + 24) = a3;
            }
            __syncthreads();
            if (tid == 0) store_u32_nowait(mydone, (unsigned)(t + 1));

            f32x4 a1[4];
#pragma unroll
            for (int nt = 0; nt < 4; ++nt) a1[nt] = (f32x4){0.f, 0.f, 0.f, 0.f};
#pragma unroll
            for (int kk = 0; kk < 16; ++kk) {
                bf16x8 a = __builtin_bit_cast(
                    bf16x8, *(const uint4*)(At + l16 * 552 + kk * 32 + quad * 8));
#pragma unroll
                for (int nt = 0; nt < 4; ++nt) {
                    int n = wave * 64 + nt * 16 + l16;
                    bf16x8 b = __builtin_bit_cast(
                        bf16x8, *(const uint4*)(w1b + (size_t)n * 512 + kk * 32 + quad * 8));
                    a1[nt] = __builtin_amdgcn_mfma_f32_16x16x32_bf16(a, b, a1[nt], 0, 0, 0);
                }
            }
#pragma unroll
            for (int nt = 0; nt < 4; ++nt) {
                int n = wave * 64 + nt * 16 + l16;
                float bv = b1[n];
#pragma unroll
                for (int r = 0; r < 4; ++r)
                    hid[(quad * 4 + r) * 264 + n] = f2bf(fmaxf(a1[nt][r] + bv, 0.f));
            }
            __syncthreads();
            if (wave == 0) {
                f32x4 a2[2];
                a2[0] = (f32x4){0.f, 0.f, 0.f, 0.f};
                a2[1] = (f32x4){0.f, 0.f, 0.f, 0.f};
#pragma unroll
                for (int kk = 0; kk < 8; ++kk) {
                    bf16x8 a = __builtin_bit_cast(
                        bf16x8, *(const uint4*)(hid + l16 * 264 + kk * 32 + quad * 8));
#pragma unroll
                    for (int nt = 0; nt < 2; ++nt) {
                        int n = nt * 16 + l16;
                        bf16x8 b;
                        if (n < NCLS) {
                            b = __builtin_bit_cast(
                                bf16x8, *(const uint4*)(w2b + (size_t)n * 256 + kk * 32 + quad * 8));
                        } else {
                            uint4 z; z.x = z.y = z.z = z.w = 0u;
                            b = __builtin_bit_cast(bf16x8, z);
                        }
                        a2[nt] = __builtin_amdgcn_mfma_f32_16x16x32_bf16(a, b, a2[nt], 0, 0, 0);
                    }
                }
#pragma unroll
                for (int nt = 0; nt < 2; ++nt) {
                    int n = nt * 16 + l16;
                    if (n < NCLS) {
                        float bv = b2[n];
#pragma unroll
                        for (int r = 0; r < 4; ++r)
                            lg[(quad * 4 + r) * 24 + n] = a2[nt][r] + bv;
                    }
                }
            }
            __syncthreads();
            if (tid < 16) {
                float v[NCLS];
                float mx = -3.4e38f;
#pragma unroll
                for (int c = 0; c < NCLS; ++c) { v[c] = lg[tid * 24 + c]; mx = fmaxf(mx, v[c]); }
                float s = 0.f;
#pragma unroll
                for (int c = 0; c < NCLS; ++c) s += __expf(v[c] - mx);
                float lse = mx + __logf(s);
                float* orow = out + ((size_t)(B0 + tid) * S_LEN + t) * NCLS;
#pragma unroll
                for (int c = 0; c < NCLS; ++c) orow[c] = v[c] - lse;
            }
            __syncthreads();
        }
    }
}

extern "C" void kernel_launch(void* const* d_in, const int* in_sizes, int n_in,
                              void* d_out, int out_size, void* d_ws, size_t ws_size,
                              hipStream_t stream) {
    const float* x    = (const float*)d_in[0];
    const float* w_ih = (const float*)d_in[1];
    const float* w_hh = (const float*)d_in[2];
    const float* b_ih = (const float*)d_in[3];
    const float* b_hh = (const float*)d_in[4];
    const float* w1   = (const float*)d_in[5];
    const float* b1   = (const float*)d_in[6];
    const float* w2   = (const float*)d_in[7];
    const float* b2   = (const float*)d_in[8];
    char* ws = (char*)d_ws;

    const size_t HS_BYTES = (size_t)16 * S_LEN * 16 * HID * 2;   // 128 MB
    const size_t NEED_BIG = HS_BYTES + 8192 + 262144 + 10240;

    if (ws_size >= NEED_BIG) {
        unsigned short* hsb   = (unsigned short*)ws;
        unsigned*       flags = (unsigned*)(ws + HS_BYTES);
        unsigned short* w1b   = (unsigned short*)(ws + HS_BYTES + 8192);
        unsigned short* w2b   = (unsigned short*)(ws + HS_BYTES + 8192 + 262144);
        prep_kernel<<<512, 256, 0, stream>>>(w1, w2, w1b, w2b, flags, 2048);
        lstm_big_kernel<<<256, 256, 0, stream>>>(x, w_ih, w_hh, b_ih, b_hh,
                                                 w1b, b1, w2b, b2,
                                                 (float*)d_out, hsb, flags);
    } else {
        unsigned short* hb    = (unsigned short*)ws;
        unsigned*       flags = (unsigned*)(ws + 4194304);
        unsigned*       done  = (unsigned*)(ws + 4194304 + 16384);
        unsigned short* w1b   = (unsigned short*)(ws + 4194304 + 16384 + 8192);
        unsigned short* w2b   = (unsigned short*)(ws + 4194304 + 16384 + 8192 + 262144);
        prep_kernel<<<512, 256, 0, stream>>>(w1, w2, w1b, w2b, flags, 6144);
        lstm_fused_kernel<<<384, 256, 0, stream>>>(x, w_ih, w_hh, b_ih, b_hh,
                                                   w1b, b1, w2b, b2,
                                                   (float*)d_out, hb, flags, done);
    }
}